// Round 14
// baseline (133.705 us; speedup 1.0000x reference)
//
#include <hip/hip_runtime.h>

// Problem constants (B=1)
#define R_   384
#define P_   (R_ * R_)      // 147456 pairs
#define NT_  4              // templates
#define CIN  128            // z channels
#define CKV  64             // t channels
#define NH   4              // heads
#define HC   256            // NH * 64

// Tiling
#define TP   64             // pairs per block (256 threads, 4 waves)
#define LDZ  136            // Z row stride (bf16) in s0 during staging/GEMM1
#define LDA  280            // T/A row stride (bf16): 560B rows

typedef __attribute__((ext_vector_type(8))) short bf16x8;
typedef __attribute__((ext_vector_type(4))) float f32x4;
typedef __attribute__((ext_vector_type(4))) uint  u32x4;
typedef __attribute__((ext_vector_type(2))) __bf16 bfv2;

#if defined(__has_builtin)
#if __has_builtin(__builtin_amdgcn_fdot2_f32_bf16)
#define HAS_DOT2BF 1
#endif
#endif

// round-to-nearest-even f32 -> bf16 (bit-level, no HIP class types)
__device__ __forceinline__ ushort f2bf_s(float f) {
    uint32_t u = __float_as_uint(f);
    u += 0x7FFFu + ((u >> 16) & 1u);
    return (ushort)(u >> 16);
}
__device__ __forceinline__ uint packbf2(float lo, float hi) {
    return (uint)f2bf_s(lo) | ((uint)f2bf_s(hi) << 16);
}
__device__ __forceinline__ uint2 pack4(const float4 v) {
    uint2 r; r.x = packbf2(v.x, v.y); r.y = packbf2(v.z, v.w); return r;
}
__device__ __forceinline__ float bflo(uint t) { return __uint_as_float(t << 16); }
__device__ __forceinline__ float bfhi(uint t) { return __uint_as_float(t & 0xffff0000u); }

__device__ __forceinline__ float dot2bf(uint a, uint b, float acc) {
#ifdef HAS_DOT2BF
    union { uint u; bfv2 v; } ua, ub;
    ua.u = a; ub.u = b;
    return __builtin_amdgcn_fdot2_f32_bf16(ua.v, ub.v, acc, false);
#else
    float r = fmaf(bflo(a), bflo(b), acc);
    return fmaf(bfhi(a), bfhi(b), r);
#endif
}

// ---------------------------------------------------------------------------
// Precompute Mt[n][ci] = C^-0.5 * sum_c Wq[ci][h*64+c] * Wk[j][h*64+c]   (n = h*64+j)
//            Gt[co][n] =         sum_c Wv[j][h*64+c] * Wo[h*64+c][co]
// ---------------------------------------------------------------------------
__global__ __launch_bounds__(256) void precompute_mg(
        const float* __restrict__ Wq, const float* __restrict__ Wk,
        const float* __restrict__ Wv, const float* __restrict__ Wo,
        ushort* __restrict__ Mt, ushort* __restrict__ Gt) {
    int tid = blockIdx.x * blockDim.x + threadIdx.x;
    if (tid < HC * CIN) {
        int n = tid >> 7, ci = tid & 127;
        int h = n >> 6, j = n & 63;
        float acc = 0.f;
        for (int c = 0; c < 64; ++c)
            acc += Wq[ci * HC + h * 64 + c] * Wk[j * HC + h * 64 + c];
        Mt[n * CIN + ci] = f2bf_s(acc * 0.125f);   // C^-0.5 = 1/8
    } else {
        int t = tid - HC * CIN;
        int co = t >> 8, n = t & 255;
        int h = n >> 6, j = n & 63;
        float acc = 0.f;
        for (int c = 0; c < 64; ++c)
            acc += Wv[j * HC + h * 64 + c] * Wo[(h * 64 + c) * CIN + co];
        Gt[co * HC + n] = f2bf_s(acc);
    }
}

// ---------------------------------------------------------------------------
// Fused kernel (r6 skeleton, LDS-lean):
//   stage Z (LDZ) + T -> LDS ; bar1 ;
//   GEMM1 swapped, wave wv -> rows [wv*16,+16) x all 256 cols (B1 per-kt) ;
//   bar2 (Z reads done) ; packed b64 spill A^T (rows wave-local) ;
//   fence (rule 18) ; middle: 4 lanes/row (q = lane>>4), T from LDS,
//   shfl_xor logit reduce ; bar3 ; GEMM2 (r6) ; bias ; store.
// ---------------------------------------------------------------------------
__global__ __launch_bounds__(256, 2) void tpa_fused(
        const float* __restrict__ z2d, const float* __restrict__ t2d,
        const ushort* __restrict__ Mt, const ushort* __restrict__ Gt,
        const float* __restrict__ bo, float* __restrict__ out) {

    __shared__ ushort s0[TP * LDA];   // Z (stride LDZ) during GEMM1, then A/U (stride LDA)
    __shared__ ushort sT[TP * LDA];   // T tile: sT[p*LDA + k*64 + c]

    const int tid  = threadIdx.x;
    const int lane = tid & 63;
    const int wv   = tid >> 6;
    const int lr   = lane & 15;
    const int g    = lane >> 4;          // 0..3
    const int g8   = g << 3;
    const int pg0  = blockIdx.x * TP;

    // ---- stage Z: 64 x 128 fp32 -> bf16 ----------------------------------
    #pragma unroll
    for (int i = 0; i < 8; ++i) {
        int idx = (i * 256 + tid) * 4, p = idx >> 7, c = idx & 127;
        float4 v = *(const float4*)(z2d + (size_t)(pg0 + p) * CIN + c);
        *(uint2*)&s0[p * LDZ + c] = pack4(v);
    }
    // ---- stage T: 4 x (64 x 64) fp32 -> bf16 -----------------------------
    #pragma unroll
    for (int k = 0; k < NT_; ++k) {
        const float* src = t2d + ((size_t)k * P_ + pg0) * CKV;
        #pragma unroll
        for (int i = 0; i < 4; ++i) {
            int idx = (i * 256 + tid) * 4, p = idx >> 6, c = idx & 63;
            float4 v = *(const float4*)(src + p * 64 + c);
            *(uint2*)&sT[p * LDA + k * 64 + c] = pack4(v);
        }
    }
    __syncthreads();   // bar1: tiles staged

    // ---- GEMM1 (swapped): wave wv -> A[wv*16..+16][0..256] ----------------
    //      mfma(B1, zf): D[row(g*4+r) = n-in-16][col(lr) = p-in-16]
    f32x4 acc1[16];
    #pragma unroll
    for (int nt = 0; nt < 16; ++nt)
        acc1[nt] = (f32x4){0.f, 0.f, 0.f, 0.f};

    #pragma unroll
    for (int kt = 0; kt < 4; ++kt) {
        bf16x8 zf = *(const bf16x8*)&s0[(wv * 16 + lr) * LDZ + kt * 32 + g8];
        bf16x8 B1k[16];
        #pragma unroll
        for (int nt = 0; nt < 16; ++nt)
            B1k[nt] = *(const bf16x8*)(Mt + (nt * 16 + lr) * CIN + kt * 32 + g8);
        #pragma unroll
        for (int nt = 0; nt < 16; ++nt)
            acc1[nt] = __builtin_amdgcn_mfma_f32_16x16x32_bf16(
                B1k[nt], zf, acc1[nt], 0, 0, 0);
    }
    __syncthreads();   // bar2: all Z reads done before A overlays s0

    // ---- spill A^T -> s0[p][n], packed b64; rows wave-local ---------------
    {
        const int p = wv * 16 + lr;
        #pragma unroll
        for (int nt = 0; nt < 16; ++nt) {
            int n0 = nt * 16 + g * 4;
            uint2 w;
            w.x = packbf2(acc1[nt][0], acc1[nt][1]);
            w.y = packbf2(acc1[nt][2], acc1[nt][3]);
            *(uint2*)&s0[p * LDA + n0] = w;
        }
    }
    // same-wave cross-lane LDS RAW: drain DS pipe, pin order (rule #18)
    asm volatile("s_waitcnt lgkmcnt(0)" ::: "memory");
    __builtin_amdgcn_sched_barrier(0);

    // ---- middle: thread (pm = wv*16+lr, q = g): 16 channels per quarter ---
    {
        const int pm = wv * 16 + lr;
        const int c0 = g * 16;

        u32x4 a2[4][2];                      // A[pm, h*64 + c0 .. +16)
        #pragma unroll
        for (int h = 0; h < 4; ++h) {
            a2[h][0] = *(const u32x4*)&s0[pm * LDA + h * 64 + c0];
            a2[h][1] = *(const u32x4*)&s0[pm * LDA + h * 64 + c0 + 8];
        }
        u32x4 tq[4][2];                      // T[k][pm, c0 .. +16)
        #pragma unroll
        for (int k = 0; k < NT_; ++k) {
            tq[k][0] = *(const u32x4*)&sT[pm * LDA + k * 64 + c0];
            tq[k][1] = *(const u32x4*)&sT[pm * LDA + k * 64 + c0 + 8];
        }

        float lg[4][4];
        #pragma unroll
        for (int h = 0; h < 4; ++h)
            #pragma unroll
            for (int k = 0; k < NT_; ++k) {
                float s = 0.f;
                #pragma unroll
                for (int j = 0; j < 2; ++j)
                    #pragma unroll
                    for (int e = 0; e < 4; ++e)
                        s = dot2bf(a2[h][j][e], tq[k][j][e], s);
                lg[h][k] = s;
            }
        // reduce partials across the 4 q-lanes (same pm: lane bits 4,5)
        #pragma unroll
        for (int h = 0; h < 4; ++h)
            #pragma unroll
            for (int k = 0; k < NT_; ++k) {
                float s = lg[h][k];
                s += __shfl_xor(s, 16);
                s += __shfl_xor(s, 32);
                lg[h][k] = s;
            }
        // softmax per h (redundant in 4 q-lanes; weights in registers)
        float wgt[4][4];
        #pragma unroll
        for (int h = 0; h < 4; ++h) {
            float mx = fmaxf(fmaxf(lg[h][0], lg[h][1]), fmaxf(lg[h][2], lg[h][3]));
            float e0 = __expf(lg[h][0] - mx), e1 = __expf(lg[h][1] - mx);
            float e2 = __expf(lg[h][2] - mx), e3 = __expf(lg[h][3] - mx);
            float inv = 1.f / (e0 + e1 + e2 + e3);
            wgt[h][0] = e0 * inv; wgt[h][1] = e1 * inv;
            wgt[h][2] = e2 * inv; wgt[h][3] = e3 * inv;
        }
        // U[pm, h*64 + c0 .. +16) from tq regs; overwrite own A slice
        #pragma unroll
        for (int h = 0; h < 4; ++h)
            #pragma unroll
            for (int j = 0; j < 2; ++j) {
                u32x4 o;
                #pragma unroll
                for (int e = 0; e < 4; ++e) {
                    uint t0 = tq[0][j][e], t1 = tq[1][j][e];
                    uint t2 = tq[2][j][e], t3 = tq[3][j][e];
                    float lo = wgt[h][0] * bflo(t0) + wgt[h][1] * bflo(t1)
                             + wgt[h][2] * bflo(t2) + wgt[h][3] * bflo(t3);
                    float hi = wgt[h][0] * bfhi(t0) + wgt[h][1] * bfhi(t1)
                             + wgt[h][2] * bfhi(t2) + wgt[h][3] * bfhi(t3);
                    o[e] = packbf2(lo, hi);
                }
                *(u32x4*)&s0[pm * LDA + h * 64 + c0 + j * 8] = o;
            }
    }
    __syncthreads();   // bar3: U visible to all waves

    // ---- B2 + bias (L2-resident; issue just before use) -------------------
    bf16x8 B2[8][2];   // [kt][nt], wave wv -> out cols [wv*32, +32)
    #pragma unroll
    for (int kt = 0; kt < 8; ++kt)
        #pragma unroll
        for (int nt = 0; nt < 2; ++nt)
            B2[kt][nt] = *(const bf16x8*)(Gt + (wv * 32 + nt * 16 + lr) * HC + kt * 32 + g8);
    const float bias0 = bo[wv * 32 + lr];
    const float bias1 = bo[wv * 32 + 16 + lr];

    // ---- GEMM2: OUT[64][128] = U[64][256] @ G ------------------------------
    f32x4 acc2[4][2];
    #pragma unroll
    for (int mt = 0; mt < 4; ++mt)
        #pragma unroll
        for (int nt = 0; nt < 2; ++nt)
            acc2[mt][nt] = (f32x4){0.f, 0.f, 0.f, 0.f};
    #pragma unroll
    for (int kt = 0; kt < 8; ++kt) {
        bf16x8 af[4];
        #pragma unroll
        for (int mt = 0; mt < 4; ++mt)
            af[mt] = *(const bf16x8*)&s0[(mt * 16 + lr) * LDA + kt * 32 + g8];
        #pragma unroll
        for (int mt = 0; mt < 4; ++mt)
            #pragma unroll
            for (int nt = 0; nt < 2; ++nt)
                acc2[mt][nt] = __builtin_amdgcn_mfma_f32_16x16x32_bf16(
                    af[mt], B2[kt][nt], acc2[mt][nt], 0, 0, 0);
    }

    // ---- epilogue: bias + fp32 store ---------------------------------------
    #pragma unroll
    for (int nt = 0; nt < 2; ++nt) {
        int co = wv * 32 + nt * 16 + lr;
        float bias = nt ? bias1 : bias0;
        #pragma unroll
        for (int mt = 0; mt < 4; ++mt) {
            int row = mt * 16 + g * 4;
            #pragma unroll
            for (int r = 0; r < 4; ++r)
                out[(size_t)(pg0 + row + r) * CIN + co] = acc2[mt][nt][r] + bias;
        }
    }
}

extern "C" void kernel_launch(void* const* d_in, const int* in_sizes, int n_in,
                              void* d_out, int out_size, void* d_ws, size_t ws_size,
                              hipStream_t stream) {
    const float* z2d = (const float*)d_in[0];
    const float* t2d = (const float*)d_in[1];
    const float* Wq  = (const float*)d_in[2];
    const float* Wk  = (const float*)d_in[3];
    const float* Wv  = (const float*)d_in[4];
    const float* Wo  = (const float*)d_in[5];
    const float* bo  = (const float*)d_in[6];

    ushort* Mt = (ushort*)d_ws;            // 256x128 bf16
    ushort* Gt = Mt + HC * CIN;            // 128x256 bf16

    precompute_mg<<<(2 * HC * CIN) / 256, 256, 0, stream>>>(Wq, Wk, Wv, Wo, Mt, Gt);
    tpa_fused<<<P_ / TP, 256, 0, stream>>>(z2d, t2d, Mt, Gt, bo, (float*)d_out);
}

// Round 15
// 88.117 us; speedup vs baseline: 1.5174x; 1.5174x over previous
//
#include <hip/hip_runtime.h>

// Problem constants (B=1)
#define R_   384
#define P_   (R_ * R_)      // 147456 pairs
#define NT_  4              // templates
#define CIN  128            // z channels
#define CKV  64             // t channels
#define NH   4              // heads
#define HC   256            // NH * 64

// Tiling
#define TP   64             // pairs per block (256 threads, 4 waves)
#define LDZ  136            // Z row stride (bf16) in s0 during staging/GEMM1
#define LDA  280            // T/U row stride (bf16): 560B rows

typedef __attribute__((ext_vector_type(8))) short bf16x8;
typedef __attribute__((ext_vector_type(4))) float f32x4;
typedef __attribute__((ext_vector_type(4))) uint  u32x4;

// round-to-nearest-even f32 -> bf16 (bit-level, no HIP class types)
__device__ __forceinline__ ushort f2bf_s(float f) {
    uint32_t u = __float_as_uint(f);
    u += 0x7FFFu + ((u >> 16) & 1u);
    return (ushort)(u >> 16);
}
__device__ __forceinline__ uint packbf2(float lo, float hi) {
    return (uint)f2bf_s(lo) | ((uint)f2bf_s(hi) << 16);
}
__device__ __forceinline__ uint2 pack4(const float4 v) {
    uint2 r; r.x = packbf2(v.x, v.y); r.y = packbf2(v.z, v.w); return r;
}
__device__ __forceinline__ float bflo(uint t) { return __uint_as_float(t << 16); }
__device__ __forceinline__ float bfhi(uint t) { return __uint_as_float(t & 0xffff0000u); }

// ---------------------------------------------------------------------------
// Precompute Mt (ROW-PERMUTED) and Gt (original order).
//   Mt logical row n = h*64 + j holds M'[ci][h*64+j] = C^-0.5 * (Wq Wk^T)
//   stored at permuted row h*64 + perm(j), perm(j) = ((j>>2)&3)*16 + (j>>4)*4
//   + (j&3), so that swapped-GEMM1's lane g ends up holding contiguous
//   original channels [g*16, g*16+16) of each head in acc registers.
//   Gt[co][n] = sum_c Wv[j][h*64+c] * Wo[h*64+c][co]  (original order).
// ---------------------------------------------------------------------------
__global__ __launch_bounds__(256) void precompute_mg(
        const float* __restrict__ Wq, const float* __restrict__ Wk,
        const float* __restrict__ Wv, const float* __restrict__ Wo,
        ushort* __restrict__ Mt, ushort* __restrict__ Gt) {
    int tid = blockIdx.x * blockDim.x + threadIdx.x;
    if (tid < HC * CIN) {
        int n = tid >> 7, ci = tid & 127;
        int h = n >> 6, j = n & 63;
        float acc = 0.f;
        for (int c = 0; c < 64; ++c)
            acc += Wq[ci * HC + h * 64 + c] * Wk[j * HC + h * 64 + c];
        int jp = ((j >> 2) & 3) * 16 + (j >> 4) * 4 + (j & 3);   // permute
        Mt[(h * 64 + jp) * CIN + ci] = f2bf_s(acc * 0.125f);     // C^-0.5 = 1/8
    } else {
        int t = tid - HC * CIN;
        int co = t >> 8, n = t & 255;
        int h = n >> 6, j = n & 63;
        float acc = 0.f;
        for (int c = 0; c < 64; ++c)
            acc += Wv[j * HC + h * 64 + c] * Wo[(h * 64 + c) * CIN + co];
        Gt[co * HC + n] = f2bf_s(acc);
    }
}

// ---------------------------------------------------------------------------
// Fused kernel: A never touches LDS.
//   hoist B1 ; stage Z,T -> LDS ; bar1 ;
//   GEMM1 swapped (acc1[nt][mt] = mfma(B1, zf)): lane (g,lr) holds
//     A[p = mt*16+lr][head wv, ch g*16 + nt*4 + r] in fp32 regs ;
//   bar2 (Z reads done) ; B2/bias issue ;
//   middle per mt: T (2 b128 per k) -> regs ; logits from fp32 acc ;
//     shfl_xor(16,32) reduce ; softmax ; U -> s0 (2 b128) ;
//   bar3 ; GEMM2 ; bias ; store.   3 barriers, no spill phase.
// ---------------------------------------------------------------------------
__global__ __launch_bounds__(256, 2) void tpa_fused(
        const float* __restrict__ z2d, const float* __restrict__ t2d,
        const ushort* __restrict__ Mt, const ushort* __restrict__ Gt,
        const float* __restrict__ bo, float* __restrict__ out) {

    __shared__ ushort s0[TP * LDA];   // Z (stride LDZ) during GEMM1, then U (stride LDA)
    __shared__ ushort sT[TP * LDA];   // T tile: sT[p*LDA + k*64 + c]

    const int tid  = threadIdx.x;
    const int lane = tid & 63;
    const int wv   = tid >> 6;           // wave == head
    const int lr   = lane & 15;
    const int g    = lane >> 4;          // 0..3
    const int g8   = g << 3;
    const int pg0  = blockIdx.x * TP;

    // ---- B1 fragments hoisted ONCE (L2-resident, permuted Mt) ------------
    bf16x8 B1[4][4];   // [kt][nt], wave wv -> head-wv rows of Mt
    #pragma unroll
    for (int kt = 0; kt < 4; ++kt)
        #pragma unroll
        for (int nt = 0; nt < 4; ++nt)
            B1[kt][nt] = *(const bf16x8*)(Mt + (wv * 64 + nt * 16 + lr) * CIN + kt * 32 + g8);

    // ---- stage Z: 64 x 128 fp32 -> bf16 ----------------------------------
    #pragma unroll
    for (int i = 0; i < 8; ++i) {
        int idx = (i * 256 + tid) * 4, p = idx >> 7, c = idx & 127;
        float4 v = *(const float4*)(z2d + (size_t)(pg0 + p) * CIN + c);
        *(uint2*)&s0[p * LDZ + c] = pack4(v);
    }
    // ---- stage T: 4 x (64 x 64) fp32 -> bf16 -----------------------------
    #pragma unroll
    for (int k = 0; k < NT_; ++k) {
        const float* src = t2d + ((size_t)k * P_ + pg0) * CKV;
        #pragma unroll
        for (int i = 0; i < 4; ++i) {
            int idx = (i * 256 + tid) * 4, p = idx >> 6, c = idx & 63;
            float4 v = *(const float4*)(src + p * 64 + c);
            *(uint2*)&sT[p * LDA + k * 64 + c] = pack4(v);
        }
    }
    __syncthreads();   // bar1: tiles staged

    // ---- GEMM1 (swapped): acc1[nt][mt]; lane holds A^T fragment -----------
    //      D[row = n-in-16 (g*4+r)][col = p-in-16 (lr)]
    f32x4 acc1[4][4];
    #pragma unroll
    for (int nt = 0; nt < 4; ++nt)
        #pragma unroll
        for (int mt = 0; mt < 4; ++mt)
            acc1[nt][mt] = (f32x4){0.f, 0.f, 0.f, 0.f};
    #pragma unroll
    for (int kt = 0; kt < 4; ++kt) {
        bf16x8 zf[4];
        #pragma unroll
        for (int mt = 0; mt < 4; ++mt)
            zf[mt] = *(const bf16x8*)&s0[(mt * 16 + lr) * LDZ + kt * 32 + g8];
        #pragma unroll
        for (int nt = 0; nt < 4; ++nt)
            #pragma unroll
            for (int mt = 0; mt < 4; ++mt)
                acc1[nt][mt] = __builtin_amdgcn_mfma_f32_16x16x32_bf16(
                    B1[kt][nt], zf[mt], acc1[nt][mt], 0, 0, 0);
    }
    __syncthreads();   // bar2: all Z reads done (U may overlay s0)

    // ---- B2 + bias (L2 latency hides under middle) ------------------------
    bf16x8 B2[8][2];   // [kt][nt], wave wv -> out cols [wv*32, +32)
    #pragma unroll
    for (int kt = 0; kt < 8; ++kt)
        #pragma unroll
        for (int nt = 0; nt < 2; ++nt)
            B2[kt][nt] = *(const bf16x8*)(Gt + (wv * 32 + nt * 16 + lr) * HC + kt * 32 + g8);
    const float bias0 = bo[wv * 32 + lr];
    const float bias1 = bo[wv * 32 + 16 + lr];

    // ---- middle: per mt, pair p = mt*16+lr; this lane owns head wv,
    //      original channels [g*16, g*16+16) (thanks to the Mt permutation:
    //      acc1[nt][mt][r] = A[p][wv*64 + g*16 + nt*4 + r], fp32)
    #pragma unroll
    for (int mt = 0; mt < 4; ++mt) {
        const int p = mt * 16 + lr;
        u32x4 tq[NT_][2];                 // T[p][k*64 + g*16 .. +16), bf16
        #pragma unroll
        for (int k = 0; k < NT_; ++k) {
            tq[k][0] = *(const u32x4*)&sT[p * LDA + k * 64 + g * 16];
            tq[k][1] = *(const u32x4*)&sT[p * LDA + k * 64 + g * 16 + 8];
        }
        float lg[4];
        #pragma unroll
        for (int k = 0; k < NT_; ++k) {
            float s = 0.f;
            #pragma unroll
            for (int nt = 0; nt < 4; ++nt)
                #pragma unroll
                for (int r = 0; r < 4; ++r) {
                    int cc = nt * 4 + r;
                    uint tw = tq[k][cc >> 3][(cc >> 1) & 3];
                    float tv = (cc & 1) ? bfhi(tw) : bflo(tw);
                    s = fmaf(acc1[nt][mt][r], tv, s);
                }
            s += __shfl_xor(s, 16);       // combine 4 g-quarters
            s += __shfl_xor(s, 32);
            lg[k] = s;
        }
        float mx = fmaxf(fmaxf(lg[0], lg[1]), fmaxf(lg[2], lg[3]));
        float w0 = __expf(lg[0] - mx), w1 = __expf(lg[1] - mx);
        float w2 = __expf(lg[2] - mx), w3 = __expf(lg[3] - mx);
        float inv = 1.f / (w0 + w1 + w2 + w3);
        w0 *= inv; w1 *= inv; w2 *= inv; w3 *= inv;

        // U[p][wv*64 + g*16 + cc] = sum_k w_k T ; write 2 b128 (orig order)
        #pragma unroll
        for (int j = 0; j < 2; ++j) {
            u32x4 o;
            #pragma unroll
            for (int e = 0; e < 4; ++e) {
                uint t0 = tq[0][j][e], t1 = tq[1][j][e];
                uint t2 = tq[2][j][e], t3 = tq[3][j][e];
                float lo = w0 * bflo(t0) + w1 * bflo(t1) + w2 * bflo(t2) + w3 * bflo(t3);
                float hi = w0 * bfhi(t0) + w1 * bfhi(t1) + w2 * bfhi(t2) + w3 * bfhi(t3);
                o[e] = packbf2(lo, hi);
            }
            *(u32x4*)&s0[p * LDA + wv * 64 + g * 16 + j * 8] = o;
        }
    }
    __syncthreads();   // bar3: U visible to all waves

    // ---- GEMM2: OUT[64][128] = U[64][256] @ G ------------------------------
    f32x4 acc2[4][2];
    #pragma unroll
    for (int mt = 0; mt < 4; ++mt)
        #pragma unroll
        for (int nt = 0; nt < 2; ++nt)
            acc2[mt][nt] = (f32x4){0.f, 0.f, 0.f, 0.f};
    #pragma unroll
    for (int kt = 0; kt < 8; ++kt) {
        bf16x8 af[4];
        #pragma unroll
        for (int mt = 0; mt < 4; ++mt)
            af[mt] = *(const bf16x8*)&s0[(mt * 16 + lr) * LDA + kt * 32 + g8];
        #pragma unroll
        for (int mt = 0; mt < 4; ++mt)
            #pragma unroll
            for (int nt = 0; nt < 2; ++nt)
                acc2[mt][nt] = __builtin_amdgcn_mfma_f32_16x16x32_bf16(
                    af[mt], B2[kt][nt], acc2[mt][nt], 0, 0, 0);
    }

    // ---- epilogue: bias + fp32 store ---------------------------------------
    #pragma unroll
    for (int nt = 0; nt < 2; ++nt) {
        int co = wv * 32 + nt * 16 + lr;
        float bias = nt ? bias1 : bias0;
        #pragma unroll
        for (int mt = 0; mt < 4; ++mt) {
            int row = mt * 16 + g * 4;
            #pragma unroll
            for (int r = 0; r < 4; ++r)
                out[(size_t)(pg0 + row + r) * CIN + co] = acc2[mt][nt][r] + bias;
        }
    }
}

extern "C" void kernel_launch(void* const* d_in, const int* in_sizes, int n_in,
                              void* d_out, int out_size, void* d_ws, size_t ws_size,
                              hipStream_t stream) {
    const float* z2d = (const float*)d_in[0];
    const float* t2d = (const float*)d_in[1];
    const float* Wq  = (const float*)d_in[2];
    const float* Wk  = (const float*)d_in[3];
    const float* Wv  = (const float*)d_in[4];
    const float* Wo  = (const float*)d_in[5];
    const float* bo  = (const float*)d_in[6];

    ushort* Mt = (ushort*)d_ws;            // 256x128 bf16 (row-permuted)
    ushort* Gt = Mt + HC * CIN;            // 128x256 bf16

    precompute_mg<<<(2 * HC * CIN) / 256, 256, 0, stream>>>(Wq, Wk, Wv, Wo, Mt, Gt);
    tpa_fused<<<P_ / TP, 256, 0, stream>>>(z2d, t2d, Mt, Gt, bo, (float*)d_out);
}

// Round 16
// 78.566 us; speedup vs baseline: 1.7018x; 1.1216x over previous
//
#include <hip/hip_runtime.h>

// Problem constants (B=1)
#define R_   384
#define P_   (R_ * R_)      // 147456 pairs
#define NT_  4              // templates
#define CIN  128            // z channels
#define CKV  64             // t channels
#define NH   4              // heads
#define HC   256            // NH * 64

// Tiling
#define TP   64             // pairs per block (256 threads, 4 waves)
#define LDZ  136            // Z row stride (bf16) in s0
#define LDT  264            // T/U row stride (bf16) in sT: 528B rows

typedef __attribute__((ext_vector_type(8))) short bf16x8;
typedef __attribute__((ext_vector_type(4))) float f32x4;
typedef __attribute__((ext_vector_type(4))) uint  u32x4;

// round-to-nearest-even f32 -> bf16 (bit-level, no HIP class types)
__device__ __forceinline__ ushort f2bf_s(float f) {
    uint32_t u = __float_as_uint(f);
    u += 0x7FFFu + ((u >> 16) & 1u);
    return (ushort)(u >> 16);
}
__device__ __forceinline__ uint packbf2(float lo, float hi) {
    return (uint)f2bf_s(lo) | ((uint)f2bf_s(hi) << 16);
}
__device__ __forceinline__ uint2 pack4(const float4 v) {
    uint2 r; r.x = packbf2(v.x, v.y); r.y = packbf2(v.z, v.w); return r;
}
__device__ __forceinline__ float bflo(uint t) { return __uint_as_float(t << 16); }
__device__ __forceinline__ float bfhi(uint t) { return __uint_as_float(t & 0xffff0000u); }

// ---------------------------------------------------------------------------
// Precompute Mt (ROW-PERMUTED, verified r15) and Gt.
//   Mt logical row n = h*64 + j stored at row h*64 + perm(j),
//   perm(j) = ((j>>2)&3)*16 + (j>>4)*4 + (j&3): swapped-GEMM1's lane g then
//   holds contiguous original channels [g*16, g*16+16) of each head.
// ---------------------------------------------------------------------------
__global__ __launch_bounds__(256) void precompute_mg(
        const float* __restrict__ Wq, const float* __restrict__ Wk,
        const float* __restrict__ Wv, const float* __restrict__ Wo,
        ushort* __restrict__ Mt, ushort* __restrict__ Gt) {
    int tid = blockIdx.x * blockDim.x + threadIdx.x;
    if (tid < HC * CIN) {
        int n = tid >> 7, ci = tid & 127;
        int h = n >> 6, j = n & 63;
        float acc = 0.f;
        for (int c = 0; c < 64; ++c)
            acc += Wq[ci * HC + h * 64 + c] * Wk[j * HC + h * 64 + c];
        int jp = ((j >> 2) & 3) * 16 + (j >> 4) * 4 + (j & 3);   // permute
        Mt[(h * 64 + jp) * CIN + ci] = f2bf_s(acc * 0.125f);     // C^-0.5 = 1/8
    } else {
        int t = tid - HC * CIN;
        int co = t >> 8, n = t & 255;
        int h = n >> 6, j = n & 63;
        float acc = 0.f;
        for (int c = 0; c < 64; ++c)
            acc += Wv[j * HC + h * 64 + c] * Wo[(h * 64 + c) * CIN + co];
        Gt[co * HC + n] = f2bf_s(acc);
    }
}

// ---------------------------------------------------------------------------
// Fused kernel, LDS = 51.2 KB -> 3 blocks/CU (the phase-interleave lever).
//   hoist B1 ; stage Z -> s0, T -> sT ; bar1 ;
//   GEMM1 swapped (A stays in fp32 regs, r15-verified) ;
//   B2/bias issue ; middle (T from sT, logits + softmax + U -> 32 regs) ;
//   bar2 (all T reads done) ; U overwrites sT in place ; bar3 ;
//   GEMM2 from sT ; bias ; store.   s0 never overwritten -> no extra barrier.
// ---------------------------------------------------------------------------
__global__ __launch_bounds__(256, 3) void tpa_fused(
        const float* __restrict__ z2d, const float* __restrict__ t2d,
        const ushort* __restrict__ Mt, const ushort* __restrict__ Gt,
        const float* __restrict__ bo, float* __restrict__ out) {

    __shared__ ushort s0[TP * LDZ];   // Z bf16: 17408 B
    __shared__ ushort sT[TP * LDT];   // T bf16, then U bf16 (in place): 33792 B

    const int tid  = threadIdx.x;
    const int lane = tid & 63;
    const int wv   = tid >> 6;           // wave == head
    const int lr   = lane & 15;
    const int g    = lane >> 4;          // 0..3
    const int g8   = g << 3;
    const int pg0  = blockIdx.x * TP;

    // ---- B1 fragments hoisted ONCE (L2-resident, permuted Mt) ------------
    bf16x8 B1[4][4];   // [kt][nt]
    #pragma unroll
    for (int kt = 0; kt < 4; ++kt)
        #pragma unroll
        for (int nt = 0; nt < 4; ++nt)
            B1[kt][nt] = *(const bf16x8*)(Mt + (wv * 64 + nt * 16 + lr) * CIN + kt * 32 + g8);

    // ---- stage Z: 64 x 128 fp32 -> bf16 ----------------------------------
    #pragma unroll
    for (int i = 0; i < 8; ++i) {
        int idx = (i * 256 + tid) * 4, p = idx >> 7, c = idx & 127;
        float4 v = *(const float4*)(z2d + (size_t)(pg0 + p) * CIN + c);
        *(uint2*)&s0[p * LDZ + c] = pack4(v);
    }
    // ---- stage T: 4 x (64 x 64) fp32 -> bf16 -----------------------------
    #pragma unroll
    for (int k = 0; k < NT_; ++k) {
        const float* src = t2d + ((size_t)k * P_ + pg0) * CKV;
        #pragma unroll
        for (int i = 0; i < 4; ++i) {
            int idx = (i * 256 + tid) * 4, p = idx >> 6, c = idx & 63;
            float4 v = *(const float4*)(src + p * 64 + c);
            *(uint2*)&sT[p * LDT + k * 64 + c] = pack4(v);
        }
    }
    __syncthreads();   // bar1: tiles staged

    // ---- GEMM1 (swapped): acc1[nt][mt]; lane (g,lr) holds, for each
    //      p = mt*16+lr:  A[p][wv*64 + g*16 + nt*4 + r]  in fp32 (permuted Mt)
    f32x4 acc1[4][4];
    #pragma unroll
    for (int nt = 0; nt < 4; ++nt)
        #pragma unroll
        for (int mt = 0; mt < 4; ++mt)
            acc1[nt][mt] = (f32x4){0.f, 0.f, 0.f, 0.f};
    #pragma unroll
    for (int kt = 0; kt < 4; ++kt) {
        bf16x8 zf[4];
        #pragma unroll
        for (int mt = 0; mt < 4; ++mt)
            zf[mt] = *(const bf16x8*)&s0[(mt * 16 + lr) * LDZ + kt * 32 + g8];
        #pragma unroll
        for (int nt = 0; nt < 4; ++nt)
            #pragma unroll
            for (int mt = 0; mt < 4; ++mt)
                acc1[nt][mt] = __builtin_amdgcn_mfma_f32_16x16x32_bf16(
                    B1[kt][nt], zf[mt], acc1[nt][mt], 0, 0, 0);
    }

    // ---- B2 + bias (L2 latency hides under middle) ------------------------
    bf16x8 B2[8][2];   // [kt][nt], wave wv -> out cols [wv*32, +32)
    #pragma unroll
    for (int kt = 0; kt < 8; ++kt)
        #pragma unroll
        for (int nt = 0; nt < 2; ++nt)
            B2[kt][nt] = *(const bf16x8*)(Gt + (wv * 32 + nt * 16 + lr) * HC + kt * 32 + g8);
    const float bias0 = bo[wv * 32 + lr];
    const float bias1 = bo[wv * 32 + 16 + lr];

    // ---- middle: per mt, pair p = mt*16+lr; lane owns head wv,
    //      channels [g*16, +16). U accumulates into regs (no LDS write yet).
    u32x4 ureg[4][2];
    #pragma unroll
    for (int mt = 0; mt < 4; ++mt) {
        const int p = mt * 16 + lr;
        u32x4 tq[NT_][2];                 // T[p][k*64 + g*16 .. +16), bf16
        #pragma unroll
        for (int k = 0; k < NT_; ++k) {
            tq[k][0] = *(const u32x4*)&sT[p * LDT + k * 64 + g * 16];
            tq[k][1] = *(const u32x4*)&sT[p * LDT + k * 64 + g * 16 + 8];
        }
        float lg[4];
        #pragma unroll
        for (int k = 0; k < NT_; ++k) {
            float s = 0.f;
            #pragma unroll
            for (int nt = 0; nt < 4; ++nt)
                #pragma unroll
                for (int r = 0; r < 4; ++r) {
                    int cc = nt * 4 + r;
                    uint tw = tq[k][cc >> 3][(cc >> 1) & 3];
                    float tv = (cc & 1) ? bfhi(tw) : bflo(tw);
                    s = fmaf(acc1[nt][mt][r], tv, s);
                }
            s += __shfl_xor(s, 16);       // combine 4 g-quarters
            s += __shfl_xor(s, 32);
            lg[k] = s;
        }
        float mx = fmaxf(fmaxf(lg[0], lg[1]), fmaxf(lg[2], lg[3]));
        float w0 = __expf(lg[0] - mx), w1 = __expf(lg[1] - mx);
        float w2 = __expf(lg[2] - mx), w3 = __expf(lg[3] - mx);
        float inv = 1.f / (w0 + w1 + w2 + w3);
        w0 *= inv; w1 *= inv; w2 *= inv; w3 *= inv;

        #pragma unroll
        for (int j = 0; j < 2; ++j) {
            u32x4 o;
            #pragma unroll
            for (int e = 0; e < 4; ++e) {
                uint t0 = tq[0][j][e], t1 = tq[1][j][e];
                uint t2 = tq[2][j][e], t3 = tq[3][j][e];
                float lo = w0 * bflo(t0) + w1 * bflo(t1) + w2 * bflo(t2) + w3 * bflo(t3);
                float hi = w0 * bfhi(t0) + w1 * bfhi(t1) + w2 * bfhi(t2) + w3 * bfhi(t3);
                o[e] = packbf2(lo, hi);
            }
            ureg[mt][j] = o;
        }
    }
    __syncthreads();   // bar2: ALL T reads done before any U overwrite

    // ---- U overwrites sT in place: row p, cols [wv*64 + g*16, +16) --------
    #pragma unroll
    for (int mt = 0; mt < 4; ++mt) {
        const int p = mt * 16 + lr;
        *(u32x4*)&sT[p * LDT + wv * 64 + g * 16]     = ureg[mt][0];
        *(u32x4*)&sT[p * LDT + wv * 64 + g * 16 + 8] = ureg[mt][1];
    }
    __syncthreads();   // bar3: U visible to all waves

    // ---- GEMM2: OUT[64][128] = U[64][256] @ G ------------------------------
    f32x4 acc2[4][2];
    #pragma unroll
    for (int mt = 0; mt < 4; ++mt)
        #pragma unroll
        for (int nt = 0; nt < 2; ++nt)
            acc2[mt][nt] = (f32x4){0.f, 0.f, 0.f, 0.f};
    #pragma unroll
    for (int kt = 0; kt < 8; ++kt) {
        bf16x8 af[4];
        #pragma unroll
        for (int mt = 0; mt < 4; ++mt)
            af[mt] = *(const bf16x8*)&sT[(mt * 16 + lr) * LDT + kt * 32 + g8];
        #pragma unroll
        for (int mt = 0; mt < 4; ++mt)
            #pragma unroll
            for (int nt = 0; nt < 2; ++nt)
                acc2[mt][nt] = __builtin_amdgcn_mfma_f32_16x16x32_bf16(
                    af[mt], B2[kt][nt], acc2[mt][nt], 0, 0, 0);
    }

    // ---- epilogue: bias + fp32 store ---------------------------------------
    #pragma unroll
    for (int nt = 0; nt < 2; ++nt) {
        int co = wv * 32 + nt * 16 + lr;
        float bias = nt ? bias1 : bias0;
        #pragma unroll
        for (int mt = 0; mt < 4; ++mt) {
            int row = mt * 16 + g * 4;
            #pragma unroll
            for (int r = 0; r < 4; ++r)
                out[(size_t)(pg0 + row + r) * CIN + co] = acc2[mt][nt][r] + bias;
        }
    }
}

extern "C" void kernel_launch(void* const* d_in, const int* in_sizes, int n_in,
                              void* d_out, int out_size, void* d_ws, size_t ws_size,
                              hipStream_t stream) {
    const float* z2d = (const float*)d_in[0];
    const float* t2d = (const float*)d_in[1];
    const float* Wq  = (const float*)d_in[2];
    const float* Wk  = (const float*)d_in[3];
    const float* Wv  = (const float*)d_in[4];
    const float* Wo  = (const float*)d_in[5];
    const float* bo  = (const float*)d_in[6];

    ushort* Mt = (ushort*)d_ws;            // 256x128 bf16 (row-permuted)
    ushort* Gt = Mt + HC * CIN;            // 128x256 bf16

    precompute_mg<<<(2 * HC * CIN) / 256, 256, 0, stream>>>(Wq, Wk, Wv, Wo, Mt, Gt);
    tpa_fused<<<P_ / TP, 256, 0, stream>>>(z2d, t2d, Mt, Gt, bo, (float*)d_out);
}